// Round 12
// baseline (146.154 us; speedup 1.0000x reference)
//
#include <hip/hip_runtime.h>

constexpr int B = 4, C = 128, H = 256, W = 512;
constexpr int HW = H * W;
constexpr int CPB = 16;  // channels per blockIdx.y slice (grid.y = 8)

typedef float f4 __attribute__((ext_vector_type(4), aligned(16)));
typedef float f2u __attribute__((ext_vector_type(2), aligned(4)));

__global__ __launch_bounds__(256) void warp_flow_kernel(
    const float* __restrict__ x, const float* __restrict__ flow,
    float* __restrict__ out) {
  // 512 blocks: 128 tiles/image (16 rows x 64 cols) x 4 images.
  // XCD-aware swizzle: XCD k owns 64 contiguous tiles (= a contiguous row
  // band of one image) -> halo rows shared within one L2.
  const int orig = blockIdx.x;
  const int swz = ((orig & 7) << 6) | (orig >> 3);  // bijective on [0,512)

  const int b = swz >> 7;        // image
  const int tid = swz & 127;     // tile within image
  const int tr = tid >> 3;       // tile row (16 rows each)
  const int tc = tid & 7;        // tile col (64 cols each)

  const int t = threadIdx.x;
  // wave = 4 rows x 16 lanes x 4 px-cols; block = 4 waves = 16 rows
  const int h = tr * 16 + ((t >> 6) << 2) + ((t & 63) >> 4);
  const int w0 = tc * 64 + (t & 15) * 4;

  // flow layout [B,2,H,W]; 4 pixels' flow as f4 (w0 multiple of 4 -> aligned)
  const int fidx = ((b * 2) * H + h) * W + w0;
  const f4 flx = *reinterpret_cast<const f4*>(flow + fidx);
  const f4 fly = *reinterpret_cast<const f4*>(flow + fidx + HW);

  float wa0[4], wb0[4], wa1[4], wb1[4];
  int o0[4], o1[4];

#pragma unroll
  for (int j = 0; j < 4; ++j) {
    const int w = w0 + j;
    // replicate reference arithmetic (fp32, align_corners=True round trip)
    const float gx = (-1.0f + 2.0f * (float)w / (float)(W - 1)) + flx[j] * 2.0f / (float)(W - 1);
    const float gy = (-1.0f + 2.0f * (float)h / (float)(H - 1)) + fly[j] * 2.0f / (float)(H - 1);
    const float fx = (gx + 1.0f) * 0.5f * (float)(W - 1);
    const float fy = (gy + 1.0f) * 0.5f * (float)(H - 1);

    const float x0f = floorf(fx), y0f = floorf(fy);
    const float x1f = x0f + 1.0f, y1f = y0f + 1.0f;
    const float wx1 = fx - x0f, wx0 = 1.0f - wx1;
    const float wy1 = fy - y0f, wy0 = 1.0f - wy1;

    const bool vx0 = (x0f >= 0.0f) && (x0f <= (float)(W - 1));
    const bool vx1 = (x1f >= 0.0f) && (x1f <= (float)(W - 1));
    const bool vy0 = (y0f >= 0.0f) && (y0f <= (float)(H - 1));
    const bool vy1 = (y1f >= 0.0f) && (y1f <= (float)(H - 1));

    float a00 = wx0 * wy0 * ((vx0 && vy0) ? 1.0f : 0.0f);
    float a10 = wx1 * wy0 * ((vx1 && vy0) ? 1.0f : 0.0f);
    float a01 = wx0 * wy1 * ((vx0 && vy1) ? 1.0f : 0.0f);
    float a11 = wx1 * wy1 * ((vx1 && vy1) ? 1.0f : 0.0f);

    const float msum = a00 + a10 + a01 + a11;
    const float mask = (msum >= 0.9999f) ? 1.0f : 0.0f;
    a00 *= mask; a10 *= mask; a01 *= mask; a11 *= mask;

    const int ix0 = min(max((int)x0f, 0), W - 1);
    const int ix1 = min(max((int)x1f, 0), W - 1);
    const int iy0 = min(max((int)y0f, 0), H - 1);
    const int iy1 = min(max((int)y1f, 0), H - 1);

    // fold column clamp into pair weights: read cols (bx, bx+1)
    const int bx = min(ix0, W - 2);
    const int d0 = ix0 - bx;
    const int d1 = ix1 - bx;
    wa0[j] = (d0 ? 0.0f : a00) + (d1 ? 0.0f : a10);
    wb0[j] = (d0 ? a00 : 0.0f) + (d1 ? a10 : 0.0f);
    wa1[j] = (d0 ? 0.0f : a01) + (d1 ? 0.0f : a11);
    wb1[j] = (d0 ? a01 : 0.0f) + (d1 ? a11 : 0.0f);

    o0[j] = iy0 * W + bx;  // row-y0 pair base (bx+1 <= W-1 in-bounds)
    o1[j] = iy1 * W + bx;  // row-y1 pair base
  }

  const int cg0 = blockIdx.y * CPB;
  const float* __restrict__ xp = x + ((size_t)b * C + cg0) * HW;
  float* __restrict__ op = out + ((size_t)b * C + cg0) * HW + h * W + w0;

#pragma unroll 4
  for (int c = 0; c < CPB; ++c) {
    const int coff = c * HW;
    f4 r;
#pragma unroll
    for (int j = 0; j < 4; ++j) {
      const f2u va = *reinterpret_cast<const f2u*>(xp + coff + o0[j]);
      const f2u vb = *reinterpret_cast<const f2u*>(xp + coff + o1[j]);
      r[j] = wa0[j] * va[0] + wb0[j] * va[1] + wa1[j] * vb[0] + wb1[j] * vb[1];
    }
    __builtin_nontemporal_store(r, reinterpret_cast<f4*>(op + coff));  // dwordx4
  }
}

extern "C" void kernel_launch(void* const* d_in, const int* in_sizes, int n_in,
                              void* d_out, int out_size, void* d_ws, size_t ws_size,
                              hipStream_t stream) {
  const float* x = (const float*)d_in[0];
  const float* flow = (const float*)d_in[1];
  float* out = (float*)d_out;
  dim3 grid(512, C / CPB);  // 128 tiles/image x 4 images, 8 channel groups
  warp_flow_kernel<<<grid, dim3(256), 0, stream>>>(x, flow, out);
}

// Round 13
// 129.176 us; speedup vs baseline: 1.1314x; 1.1314x over previous
//
#include <hip/hip_runtime.h>

constexpr int B = 4, C = 128, H = 256, W = 512;
constexpr int HW = H * W;
constexpr int CPB = 32;  // channels per blockIdx.y slice (grid.y = 4)

typedef float f4 __attribute__((ext_vector_type(4), aligned(16)));
typedef float f2u __attribute__((ext_vector_type(2), aligned(4)));

__global__ __launch_bounds__(256) void warp_flow_kernel(
    const float* __restrict__ x, const float* __restrict__ flow,
    float* __restrict__ out) {
  // 512 blocks: 128 tiles/image (16 rows x 64 cols) x 4 images.
  // XCD-aware swizzle: XCD k owns 64 contiguous tiles (= a contiguous row
  // band of one image) -> halo rows shared within one L2.
  const int orig = blockIdx.x;
  const int swz = ((orig & 7) << 6) | (orig >> 3);  // bijective on [0,512)

  const int b = swz >> 7;        // image
  const int tid = swz & 127;     // tile within image
  const int tr = tid >> 3;       // tile row (16 rows each)
  const int tc = tid & 7;        // tile col (64 cols each)

  const int t = threadIdx.x;
  // wave = 4 rows x 16 lanes x 4 px-cols; block = 4 waves = 16 rows
  const int h = tr * 16 + ((t >> 6) << 2) + ((t & 63) >> 4);
  const int w0 = tc * 64 + (t & 15) * 4;

  // flow layout [B,2,H,W]; 4 pixels' flow as f4 (w0 multiple of 4 -> aligned)
  const int fidx = ((b * 2) * H + h) * W + w0;
  const f4 flx = *reinterpret_cast<const f4*>(flow + fidx);
  const f4 fly = *reinterpret_cast<const f4*>(flow + fidx + HW);

  float wa0[4], wb0[4], wa1[4], wb1[4];
  int o0[4], o1[4];

#pragma unroll
  for (int j = 0; j < 4; ++j) {
    const int w = w0 + j;
    // replicate reference arithmetic (fp32, align_corners=True round trip)
    const float gx = (-1.0f + 2.0f * (float)w / (float)(W - 1)) + flx[j] * 2.0f / (float)(W - 1);
    const float gy = (-1.0f + 2.0f * (float)h / (float)(H - 1)) + fly[j] * 2.0f / (float)(H - 1);
    const float fx = (gx + 1.0f) * 0.5f * (float)(W - 1);
    const float fy = (gy + 1.0f) * 0.5f * (float)(H - 1);

    const float x0f = floorf(fx), y0f = floorf(fy);
    const float x1f = x0f + 1.0f, y1f = y0f + 1.0f;
    const float wx1 = fx - x0f, wx0 = 1.0f - wx1;
    const float wy1 = fy - y0f, wy0 = 1.0f - wy1;

    const bool vx0 = (x0f >= 0.0f) && (x0f <= (float)(W - 1));
    const bool vx1 = (x1f >= 0.0f) && (x1f <= (float)(W - 1));
    const bool vy0 = (y0f >= 0.0f) && (y0f <= (float)(H - 1));
    const bool vy1 = (y1f >= 0.0f) && (y1f <= (float)(H - 1));

    float a00 = wx0 * wy0 * ((vx0 && vy0) ? 1.0f : 0.0f);
    float a10 = wx1 * wy0 * ((vx1 && vy0) ? 1.0f : 0.0f);
    float a01 = wx0 * wy1 * ((vx0 && vy1) ? 1.0f : 0.0f);
    float a11 = wx1 * wy1 * ((vx1 && vy1) ? 1.0f : 0.0f);

    const float msum = a00 + a10 + a01 + a11;
    const float mask = (msum >= 0.9999f) ? 1.0f : 0.0f;
    a00 *= mask; a10 *= mask; a01 *= mask; a11 *= mask;

    const int ix0 = min(max((int)x0f, 0), W - 1);
    const int ix1 = min(max((int)x1f, 0), W - 1);
    const int iy0 = min(max((int)y0f, 0), H - 1);
    const int iy1 = min(max((int)y1f, 0), H - 1);

    // fold column clamp into pair weights: read cols (bx, bx+1)
    const int bx = min(ix0, W - 2);
    const int d0 = ix0 - bx;
    const int d1 = ix1 - bx;
    wa0[j] = (d0 ? 0.0f : a00) + (d1 ? 0.0f : a10);
    wb0[j] = (d0 ? a00 : 0.0f) + (d1 ? a10 : 0.0f);
    wa1[j] = (d0 ? 0.0f : a01) + (d1 ? 0.0f : a11);
    wb1[j] = (d0 ? a01 : 0.0f) + (d1 ? a11 : 0.0f);

    o0[j] = iy0 * W + bx;  // row-y0 pair base (bx+1 <= W-1 in-bounds)
    o1[j] = iy1 * W + bx;  // row-y1 pair base
  }

  const int cg0 = blockIdx.y * CPB;
  const float* __restrict__ xp = x + ((size_t)b * C + cg0) * HW;
  float* __restrict__ op = out + ((size_t)b * C + cg0) * HW + h * W + w0;

#pragma unroll 2
  for (int c = 0; c < CPB; ++c) {
    const int coff = c * HW;
    f4 r;
#pragma unroll
    for (int j = 0; j < 4; ++j) {
      const f2u va = *reinterpret_cast<const f2u*>(xp + coff + o0[j]);
      const f2u vb = *reinterpret_cast<const f2u*>(xp + coff + o1[j]);
      r[j] = wa0[j] * va[0] + wb0[j] * va[1] + wa1[j] * vb[0] + wb1[j] * vb[1];
    }
    __builtin_nontemporal_store(r, reinterpret_cast<f4*>(op + coff));  // dwordx4
  }
}

extern "C" void kernel_launch(void* const* d_in, const int* in_sizes, int n_in,
                              void* d_out, int out_size, void* d_ws, size_t ws_size,
                              hipStream_t stream) {
  const float* x = (const float*)d_in[0];
  const float* flow = (const float*)d_in[1];
  float* out = (float*)d_out;
  dim3 grid(512, C / CPB);  // 128 tiles/image x 4 images, 4 channel groups
  warp_flow_kernel<<<grid, dim3(256), 0, stream>>>(x, flow, out);
}